// Round 2
// baseline (925.405 us; speedup 1.0000x reference)
//
#include <hip/hip_runtime.h>
#include <math.h>
#include <stdint.h>

#define DI static __device__ __forceinline__

typedef __bf16 bf16x8 __attribute__((ext_vector_type(8)));
typedef float f32x4 __attribute__((ext_vector_type(4)));
typedef float float4v __attribute__((ext_vector_type(4)));
typedef unsigned short u16;
typedef unsigned short u16x4 __attribute__((ext_vector_type(4)));

// ---- bf16 <-> f32 bit helpers (RNE) ----
DI float b2f(u16 s) {
    unsigned u = ((unsigned)s) << 16;
    float f;
    __builtin_memcpy(&f, &u, 4);
    return f;
}
DI u16 f2b(float f) {
    unsigned x;
    __builtin_memcpy(&x, &f, 4);
    unsigned r = x + 0x7FFFu + ((x >> 16) & 1u);
    return (u16)(r >> 16);
}

// ---- async global->LDS, 16B/lane; LDS dest = wave-uniform base + lane*16 ----
DI void gl_lds(const u16* g, u16* l) {
    __builtin_amdgcn_global_load_lds(
        (__attribute__((address_space(1))) void*)g,
        (__attribute__((address_space(3))) void*)l,
        16, 0, 0);
}

DI float fast_tanh(float x) {
    float xc = fminf(fmaxf(x, -15.f), 15.f);
    float e = __expf(2.0f * xc);
    return (e - 1.f) / (e + 1.f);
}

// ============ pack kernels ============
// A = [input | hx] rows -> hi/lo bf16 split. grid = B rows, block = 384.
__global__ void pack_A(const float* __restrict__ inp, const float* __restrict__ hx,
                       u16* __restrict__ Ahi, u16* __restrict__ Alo) {
    const int r = blockIdx.x;
    const int k = threadIdx.x * 4;
    float4v v = (k < 1024) ? *(const float4v*)(inp + (size_t)r * 1024 + k)
                           : *(const float4v*)(hx + (size_t)r * 512 + (k - 1024));
    u16x4 h, l;
#pragma unroll
    for (int e = 0; e < 4; ++e) {
        h[e] = f2b(v[e]);
        l[e] = f2b(v[e] - b2f(h[e]));
    }
    *(u16x4*)(Ahi + (size_t)r * 1536 + k) = h;
    *(u16x4*)(Alo + (size_t)r * 1536 + k) = l;
}

// W = [w_x | w_h] rows -> Whi (all 8192 rows) + Wlo only for i (rows 0..2048)
// and c (rows 4096..6144), stored compacted: Wlo row = h (i) / 2048+h (c).
__global__ void pack_W(const float* __restrict__ wx, const float* __restrict__ wh,
                       u16* __restrict__ Whi, u16* __restrict__ Wlo) {
    const int g = blockIdx.x;
    const int k = threadIdx.x * 4;
    float4v v = (k < 1024) ? *(const float4v*)(wx + (size_t)g * 1024 + k)
                           : *(const float4v*)(wh + (size_t)g * 512 + (k - 1024));
    u16x4 h, l;
#pragma unroll
    for (int e = 0; e < 4; ++e) {
        h[e] = f2b(v[e]);
        l[e] = f2b(v[e] - b2f(h[e]));
    }
    *(u16x4*)(Whi + (size_t)g * 1536 + k) = h;
    int lr = -1;
    if (g < 2048) lr = g;
    else if (g >= 4096 && g < 6144) lr = g - 2048;
    if (lr >= 0) *(u16x4*)(Wlo + (size_t)lr * 1536 + k) = l;
}

__global__ void pack_flat_bf16(const float* __restrict__ src, u16* __restrict__ dst) {
    const size_t t = ((size_t)blockIdx.x * blockDim.x + threadIdx.x) * 4;
    float4v v = *(const float4v*)(src + t);
    u16x4 o;
#pragma unroll
    for (int e = 0; e < 4; ++e) o[e] = f2b(v[e]);
    *(u16x4*)(dst + t) = o;
}

// ============ G1: f,o gates, plain bf16 m97-recipe NT GEMM ============
// grid (32, 64): bx<16 -> f (W rows 2048+), bx>=16 -> o (W rows 6144+).
// out: G_fo bf16 [B, 4096], f at cols [0,2048), o at [2048,4096).
__global__ __launch_bounds__(256) void gemm_fo(const u16* __restrict__ A,
                                               const u16* __restrict__ W,
                                               const float* __restrict__ bxv,
                                               const float* __restrict__ bhv,
                                               u16* __restrict__ out) {
    constexpr int K = 1536, BK = 32;
    __shared__ u16 As[128 * BK];
    __shared__ u16 Ws[128 * BK];

    const int tid = threadIdx.x, wave = tid >> 6, lane = tid & 63;
    const size_t tileM = (size_t)blockIdx.y * 128;
    const int bxi = blockIdx.x;
    const size_t wrow0 = (bxi < 16) ? (2048 + (size_t)bxi * 128)
                                    : (6144 + (size_t)(bxi - 16) * 128);
    const size_t ncol0 = (size_t)bxi * 128;
    const int waveM = (wave >> 1) * 64;
    const int waveN = (wave & 1) * 64;

    const int srow = lane >> 2, scol = (lane & 3) * 8;
    const u16* Ag = A + (tileM + (size_t)(wave * 16 + srow)) * K + scol;
    const u16* Wg = W + (wrow0 + (size_t)(wave * 16 + srow)) * K + scol;
    u16* AsB0 = &As[(wave * 16) * BK];
    u16* AsB1 = &As[(wave * 16 + 64) * BK];
    u16* WsB0 = &Ws[(wave * 16) * BK];
    u16* WsB1 = &Ws[(wave * 16 + 64) * BK];

    f32x4 acc[4][4] = {};
    const int arow = waveM + (lane & 15);
    const int wrow = waveN + (lane & 15);
    const int kq = (lane >> 4) * 8;

    for (int k0 = 0; k0 < K; k0 += BK) {
        gl_lds(Ag + k0, AsB0);
        gl_lds(Ag + (size_t)64 * K + k0, AsB1);
        gl_lds(Wg + k0, WsB0);
        gl_lds(Wg + (size_t)64 * K + k0, WsB1);
        __syncthreads();
        bf16x8 af[4], wf[4];
#pragma unroll
        for (int i = 0; i < 4; ++i) af[i] = *(const bf16x8*)&As[(arow + i * 16) * BK + kq];
#pragma unroll
        for (int j = 0; j < 4; ++j) wf[j] = *(const bf16x8*)&Ws[(wrow + j * 16) * BK + kq];
#pragma unroll
        for (int i = 0; i < 4; ++i)
#pragma unroll
            for (int j = 0; j < 4; ++j)
                acc[i][j] = __builtin_amdgcn_mfma_f32_16x16x32_bf16(af[i], wf[j], acc[i][j], 0, 0, 0);
        __syncthreads();
    }

    const int rq = (lane >> 4) * 4;
#pragma unroll
    for (int i = 0; i < 4; ++i) {
        const size_t rbase = tileM + waveM + i * 16 + rq;
#pragma unroll
        for (int j = 0; j < 4; ++j) {
            const int nl = waveN + (lane & 15) + j * 16;
            const float bias = bxv[wrow0 + nl] + bhv[wrow0 + nl];
#pragma unroll
            for (int v = 0; v < 4; ++v)
                out[(rbase + v) * 4096 + ncol0 + nl] = f2b(acc[i][j][v] + bias);
        }
    }
}

// ============ G2: i,c gates in split bf16 (hi*hi + lo*hi + hi*lo) + fused cell ============
// grid (32, 64): h-tile = 64 (blockIdx.x), M-tile = 128 (blockIdx.y).
// epilogue: ct = f*cx + i*c (f32 -> d_out), U = bf16(o * tanh(ct)) -> ws.
__global__ __launch_bounds__(256) void gemm_ic_cell(
    const u16* __restrict__ Ahi, const u16* __restrict__ Alo,
    const u16* __restrict__ Whi, const u16* __restrict__ Wlo,
    const float* __restrict__ bxv, const float* __restrict__ bhv,
    const u16* __restrict__ Gfo, const float* __restrict__ cx,
    float* __restrict__ ct, u16* __restrict__ U) {
    constexpr int K = 1536, BK = 32;
    __shared__ u16 sAh[128 * BK], sAl[128 * BK];
    __shared__ u16 sWih[64 * BK], sWil[64 * BK], sWch[64 * BK], sWcl[64 * BK];

    const int tid = threadIdx.x, wave = tid >> 6, lane = tid & 63;
    const size_t tileM = (size_t)blockIdx.y * 128;
    const size_t h0 = (size_t)blockIdx.x * 64;
    const int waveM = (wave >> 1) * 64;
    const int waveH = (wave & 1) * 32;

    const int srow = lane >> 2, scol = (lane & 3) * 8;
    const size_t wr = (size_t)(wave * 16 + srow);
    const u16* gAh = Ahi + (tileM + wr) * K + scol;
    const u16* gAl = Alo + (tileM + wr) * K + scol;
    const u16* gWih = Whi + (h0 + wr) * K + scol;
    const u16* gWch = Whi + (4096 + h0 + wr) * K + scol;
    const u16* gWil = Wlo + (h0 + wr) * K + scol;
    const u16* gWcl = Wlo + (2048 + h0 + wr) * K + scol;
    u16* lAh0 = &sAh[(wave * 16) * BK];
    u16* lAh1 = &sAh[(wave * 16 + 64) * BK];
    u16* lAl0 = &sAl[(wave * 16) * BK];
    u16* lAl1 = &sAl[(wave * 16 + 64) * BK];
    u16* lWih = &sWih[(wave * 16) * BK];
    u16* lWil = &sWil[(wave * 16) * BK];
    u16* lWch = &sWch[(wave * 16) * BK];
    u16* lWcl = &sWcl[(wave * 16) * BK];

    f32x4 ai[4][2] = {}, ac[4][2] = {};
    const int arow = waveM + (lane & 15);
    const int wrow = waveH + (lane & 15);
    const int kq = (lane >> 4) * 8;

    for (int k0 = 0; k0 < K; k0 += BK) {
        gl_lds(gAh + k0, lAh0);
        gl_lds(gAh + (size_t)64 * K + k0, lAh1);
        gl_lds(gAl + k0, lAl0);
        gl_lds(gAl + (size_t)64 * K + k0, lAl1);
        gl_lds(gWih + k0, lWih);
        gl_lds(gWil + k0, lWil);
        gl_lds(gWch + k0, lWch);
        gl_lds(gWcl + k0, lWcl);
        __syncthreads();

        bf16x8 ah[4], al[4], wih[2], wil[2], wch[2], wcl[2];
#pragma unroll
        for (int i = 0; i < 4; ++i) {
            ah[i] = *(const bf16x8*)&sAh[(arow + i * 16) * BK + kq];
            al[i] = *(const bf16x8*)&sAl[(arow + i * 16) * BK + kq];
        }
#pragma unroll
        for (int j = 0; j < 2; ++j) {
            wih[j] = *(const bf16x8*)&sWih[(wrow + j * 16) * BK + kq];
            wil[j] = *(const bf16x8*)&sWil[(wrow + j * 16) * BK + kq];
            wch[j] = *(const bf16x8*)&sWch[(wrow + j * 16) * BK + kq];
            wcl[j] = *(const bf16x8*)&sWcl[(wrow + j * 16) * BK + kq];
        }
#pragma unroll
        for (int i = 0; i < 4; ++i)
#pragma unroll
            for (int j = 0; j < 2; ++j) {
                ai[i][j] = __builtin_amdgcn_mfma_f32_16x16x32_bf16(ah[i], wih[j], ai[i][j], 0, 0, 0);
                ai[i][j] = __builtin_amdgcn_mfma_f32_16x16x32_bf16(al[i], wih[j], ai[i][j], 0, 0, 0);
                ai[i][j] = __builtin_amdgcn_mfma_f32_16x16x32_bf16(ah[i], wil[j], ai[i][j], 0, 0, 0);
                ac[i][j] = __builtin_amdgcn_mfma_f32_16x16x32_bf16(ah[i], wch[j], ac[i][j], 0, 0, 0);
                ac[i][j] = __builtin_amdgcn_mfma_f32_16x16x32_bf16(al[i], wch[j], ac[i][j], 0, 0, 0);
                ac[i][j] = __builtin_amdgcn_mfma_f32_16x16x32_bf16(ah[i], wcl[j], ac[i][j], 0, 0, 0);
            }
        __syncthreads();
    }

    // epilogue + fused LSTM cell
    const int rq = (lane >> 4) * 4;
#pragma unroll
    for (int j = 0; j < 2; ++j) {
        const size_t h = h0 + waveH + j * 16 + (lane & 15);
        const float bi = bxv[h] + bhv[h];
        const float bc = bxv[4096 + h] + bhv[4096 + h];
#pragma unroll
        for (int i = 0; i < 4; ++i) {
            const size_t m0 = tileM + waveM + i * 16 + rq;
#pragma unroll
            for (int v = 0; v < 4; ++v) {
                const size_t m = m0 + v;
                const float iv = ai[i][j][v] + bi;
                const float cv = ac[i][j][v] + bc;
                const float f = b2f(Gfo[m * 4096 + h]);
                const float o = b2f(Gfo[m * 4096 + 2048 + h]);
                const float c_ = f * cx[m * 2048 + h] + iv * cv;
                ct[m * 2048 + h] = c_;
                U[m * 2048 + h] = f2b(o * fast_tanh(c_));
            }
        }
    }
}

// ============ proj: ht[B,512] = U[B,2048] * Wp[512,2048]^T, f32 out ============
// BN=64 tiles -> grid (8,64) = 512 blocks (2 blocks/CU).
__global__ __launch_bounds__(256) void gemm_proj(const u16* __restrict__ A,
                                                 const u16* __restrict__ W,
                                                 float* __restrict__ out) {
    constexpr int K = 2048, BK = 32;
    __shared__ u16 As[128 * BK];
    __shared__ u16 Ws[64 * BK];

    const int tid = threadIdx.x, wave = tid >> 6, lane = tid & 63;
    const size_t tileM = (size_t)blockIdx.y * 128;
    const size_t tileN = (size_t)blockIdx.x * 64;
    const int waveM = (wave >> 1) * 64;
    const int waveN = (wave & 1) * 32;

    const int srow = lane >> 2, scol = (lane & 3) * 8;
    const u16* Ag = A + (tileM + (size_t)(wave * 16 + srow)) * K + scol;
    const u16* Wg = W + (tileN + (size_t)(wave * 16 + srow)) * K + scol;
    u16* AsB0 = &As[(wave * 16) * BK];
    u16* AsB1 = &As[(wave * 16 + 64) * BK];
    u16* WsB0 = &Ws[(wave * 16) * BK];

    f32x4 acc[4][2] = {};
    const int arow = waveM + (lane & 15);
    const int wrow = waveN + (lane & 15);
    const int kq = (lane >> 4) * 8;

    for (int k0 = 0; k0 < K; k0 += BK) {
        gl_lds(Ag + k0, AsB0);
        gl_lds(Ag + (size_t)64 * K + k0, AsB1);
        gl_lds(Wg + k0, WsB0);
        __syncthreads();
        bf16x8 af[4], wf[2];
#pragma unroll
        for (int i = 0; i < 4; ++i) af[i] = *(const bf16x8*)&As[(arow + i * 16) * BK + kq];
#pragma unroll
        for (int j = 0; j < 2; ++j) wf[j] = *(const bf16x8*)&Ws[(wrow + j * 16) * BK + kq];
#pragma unroll
        for (int i = 0; i < 4; ++i)
#pragma unroll
            for (int j = 0; j < 2; ++j)
                acc[i][j] = __builtin_amdgcn_mfma_f32_16x16x32_bf16(af[i], wf[j], acc[i][j], 0, 0, 0);
        __syncthreads();
    }

    const int rq = (lane >> 4) * 4;
#pragma unroll
    for (int i = 0; i < 4; ++i) {
        const size_t rbase = tileM + waveM + i * 16 + rq;
#pragma unroll
        for (int j = 0; j < 2; ++j) {
            const size_t n = tileN + waveN + (lane & 15) + j * 16;
#pragma unroll
            for (int v = 0; v < 4; ++v)
                out[(rbase + v) * 512 + n] = acc[i][j][v];
        }
    }
}

// ============ launch ============
extern "C" void kernel_launch(void* const* d_in, const int* in_sizes, int n_in,
                              void* d_out, int out_size, void* d_ws, size_t ws_size,
                              hipStream_t stream) {
    const float* input  = (const float*)d_in[0];
    const float* hx     = (const float*)d_in[1];
    const float* cx     = (const float*)d_in[2];
    const float* w_x    = (const float*)d_in[3];
    const float* b_x    = (const float*)d_in[4];
    const float* w_h    = (const float*)d_in[5];
    const float* b_h    = (const float*)d_in[6];
    const float* w_proj = (const float*)d_in[7];

    constexpr int H = 2048, P = 512, B = 8192;

    // ws layout (bytes), total 190,840,832
    char* ws = (char*)d_ws;
    u16* Ahi = (u16*)(ws);                 // [8192,1536] 25,165,824
    u16* Alo = (u16*)(ws + 25165824);      // [8192,1536] 25,165,824
    u16* Whi = (u16*)(ws + 50331648);      // [8192,1536] 25,165,824
    u16* Wlo = (u16*)(ws + 75497472);      // [4096,1536] 12,582,912 (i,c rows)
    u16* Gfo = (u16*)(ws + 88080384);      // [8192,4096] 67,108,864 (f|o bf16)
    u16* U   = (u16*)(ws + 155189248);     // [8192,2048] 33,554,432
    u16* Wp  = (u16*)(ws + 188743680);     // [512,2048]   2,097,152

    float* ht = (float*)d_out;                   // [B, P]
    float* ct = (float*)d_out + (size_t)B * P;   // [B, H]

    pack_A<<<B, 384, 0, stream>>>(input, hx, Ahi, Alo);
    pack_W<<<4 * H, 384, 0, stream>>>(w_x, w_h, Whi, Wlo);
    pack_flat_bf16<<<(P * H / 4) / 256, 256, 0, stream>>>(w_proj, Wp);

    gemm_fo<<<dim3(32, 64), 256, 0, stream>>>(Ahi, Whi, b_x, b_h, Gfo);
    gemm_ic_cell<<<dim3(32, 64), 256, 0, stream>>>(Ahi, Alo, Whi, Wlo, b_x, b_h,
                                                   Gfo, cx, ct, U);
    gemm_proj<<<dim3(8, 64), 256, 0, stream>>>(U, Wp, ht);
}

// Round 3
// 924.033 us; speedup vs baseline: 1.0015x; 1.0015x over previous
//
#include <hip/hip_runtime.h>
#include <math.h>
#include <stdint.h>

#define DI static __device__ __forceinline__

typedef __bf16 bf16x8 __attribute__((ext_vector_type(8)));
typedef float f32x4 __attribute__((ext_vector_type(4)));
typedef float float4v __attribute__((ext_vector_type(4)));
typedef unsigned short u16;
typedef unsigned short u16x4 __attribute__((ext_vector_type(4)));

// ---- bf16 <-> f32 bit helpers (RNE) ----
DI float b2f(u16 s) {
    unsigned u = ((unsigned)s) << 16;
    float f;
    __builtin_memcpy(&f, &u, 4);
    return f;
}
DI u16 f2b(float f) {
    unsigned x;
    __builtin_memcpy(&x, &f, 4);
    unsigned r = x + 0x7FFFu + ((x >> 16) & 1u);
    return (u16)(r >> 16);
}

// ---- async global->LDS, 16B/lane; LDS dest = wave-uniform base + lane*16 ----
DI void gl_lds(const u16* g, u16* l) {
    __builtin_amdgcn_global_load_lds(
        (__attribute__((address_space(1))) void*)g,
        (__attribute__((address_space(3))) void*)l,
        16, 0, 0);
}

DI float fast_tanh(float x) {
    float xc = fminf(fmaxf(x, -15.f), 15.f);
    float e = __expf(2.0f * xc);
    return (e - 1.f) / (e + 1.f);
}

// ============ pack kernels ============
__global__ void pack_A(const float* __restrict__ inp, const float* __restrict__ hx,
                       u16* __restrict__ Ahi, u16* __restrict__ Alo) {
    const int r = blockIdx.x;
    const int k = threadIdx.x * 4;
    float4v v = (k < 1024) ? *(const float4v*)(inp + (size_t)r * 1024 + k)
                           : *(const float4v*)(hx + (size_t)r * 512 + (k - 1024));
    u16x4 h, l;
#pragma unroll
    for (int e = 0; e < 4; ++e) {
        h[e] = f2b(v[e]);
        l[e] = f2b(v[e] - b2f(h[e]));
    }
    *(u16x4*)(Ahi + (size_t)r * 1536 + k) = h;
    *(u16x4*)(Alo + (size_t)r * 1536 + k) = l;
}

// Whi all 8192 gate-rows; Wlo compacted: rows [0,2048)=i-lo, [2048,4096)=c-lo.
__global__ void pack_W(const float* __restrict__ wx, const float* __restrict__ wh,
                       u16* __restrict__ Whi, u16* __restrict__ Wlo) {
    const int g = blockIdx.x;
    const int k = threadIdx.x * 4;
    float4v v = (k < 1024) ? *(const float4v*)(wx + (size_t)g * 1024 + k)
                           : *(const float4v*)(wh + (size_t)g * 512 + (k - 1024));
    u16x4 h, l;
#pragma unroll
    for (int e = 0; e < 4; ++e) {
        h[e] = f2b(v[e]);
        l[e] = f2b(v[e] - b2f(h[e]));
    }
    *(u16x4*)(Whi + (size_t)g * 1536 + k) = h;
    int lr = -1;
    if (g < 2048) lr = g;
    else if (g >= 4096 && g < 6144) lr = g - 2048;
    if (lr >= 0) *(u16x4*)(Wlo + (size_t)lr * 1536 + k) = l;
}

__global__ void pack_flat_bf16(const float* __restrict__ src, u16* __restrict__ dst) {
    const size_t t = ((size_t)blockIdx.x * blockDim.x + threadIdx.x) * 4;
    float4v v = *(const float4v*)(src + t);
    u16x4 o;
#pragma unroll
    for (int e = 0; e < 4; ++e) o[e] = f2b(v[e]);
    *(u16x4*)(dst + t) = o;
}

// ---- XCD swizzle: linear id -> (bx in [0,32), by in [0,64)) ----
// xcd = id&7 (HW round-robin); each XCD owns 4 contiguous bx values so its
// resident W streams (4 x 768 KiB = 3 MB) fit the 4 MiB per-XCD L2, and the
// 4 concurrent bx-blocks per by share one hot A-tile.
DI void swizzle2048(int id, int& bx, int& by) {
    const int xcd = id & 7;
    const int j = id >> 3;        // 0..255
    bx = xcd * 4 + (j & 3);
    by = j >> 2;
}

// ============ G1: f,o gates, plain bf16 m97-recipe NT GEMM ============
// linear grid 2048; bx<16 -> f (W rows 2048+), bx>=16 -> o (W rows 6144+).
__global__ __launch_bounds__(256) void gemm_fo(const u16* __restrict__ A,
                                               const u16* __restrict__ W,
                                               const float* __restrict__ bxv,
                                               const float* __restrict__ bhv,
                                               u16* __restrict__ out) {
    constexpr int K = 1536, BK = 32;
    __shared__ u16 As[128 * BK];
    __shared__ u16 Ws[128 * BK];

    const int tid = threadIdx.x, wave = tid >> 6, lane = tid & 63;
    int bxi, byi;
    swizzle2048(blockIdx.x, bxi, byi);
    const size_t tileM = (size_t)byi * 128;
    const size_t wrow0 = (bxi < 16) ? (2048 + (size_t)bxi * 128)
                                    : (6144 + (size_t)(bxi - 16) * 128);
    const size_t ncol0 = (size_t)bxi * 128;
    const int waveM = (wave >> 1) * 64;
    const int waveN = (wave & 1) * 64;

    const int srow = lane >> 2, scol = (lane & 3) * 8;
    const u16* Ag = A + (tileM + (size_t)(wave * 16 + srow)) * K + scol;
    const u16* Wg = W + (wrow0 + (size_t)(wave * 16 + srow)) * K + scol;
    u16* AsB0 = &As[(wave * 16) * BK];
    u16* AsB1 = &As[(wave * 16 + 64) * BK];
    u16* WsB0 = &Ws[(wave * 16) * BK];
    u16* WsB1 = &Ws[(wave * 16 + 64) * BK];

    f32x4 acc[4][4] = {};
    const int arow = waveM + (lane & 15);
    const int wrow = waveN + (lane & 15);
    const int kq = (lane >> 4) * 8;

    for (int k0 = 0; k0 < K; k0 += BK) {
        gl_lds(Ag + k0, AsB0);
        gl_lds(Ag + (size_t)64 * K + k0, AsB1);
        gl_lds(Wg + k0, WsB0);
        gl_lds(Wg + (size_t)64 * K + k0, WsB1);
        __syncthreads();
        bf16x8 af[4], wf[4];
#pragma unroll
        for (int i = 0; i < 4; ++i) af[i] = *(const bf16x8*)&As[(arow + i * 16) * BK + kq];
#pragma unroll
        for (int j = 0; j < 4; ++j) wf[j] = *(const bf16x8*)&Ws[(wrow + j * 16) * BK + kq];
#pragma unroll
        for (int i = 0; i < 4; ++i)
#pragma unroll
            for (int j = 0; j < 4; ++j)
                acc[i][j] = __builtin_amdgcn_mfma_f32_16x16x32_bf16(af[i], wf[j], acc[i][j], 0, 0, 0);
        __syncthreads();
    }

    const int rq = (lane >> 4) * 4;
#pragma unroll
    for (int i = 0; i < 4; ++i) {
        const size_t rbase = tileM + waveM + i * 16 + rq;
#pragma unroll
        for (int j = 0; j < 4; ++j) {
            const int nl = waveN + (lane & 15) + j * 16;
            const float bias = bxv[wrow0 + nl] + bhv[wrow0 + nl];
#pragma unroll
            for (int v = 0; v < 4; ++v)
                out[(rbase + v) * 4096 + ncol0 + nl] = f2b(acc[i][j][v] + bias);
        }
    }
}

// ============ G2: i,c gates split-bf16 (hi*hi + lo*hi + hi*lo) + fused cell ============
__global__ __launch_bounds__(256) void gemm_ic_cell(
    const u16* __restrict__ Ahi, const u16* __restrict__ Alo,
    const u16* __restrict__ Whi, const u16* __restrict__ Wlo,
    const float* __restrict__ bxv, const float* __restrict__ bhv,
    const u16* __restrict__ Gfo, const float* __restrict__ cx,
    float* __restrict__ ct, u16* __restrict__ U) {
    constexpr int K = 1536, BK = 32;
    __shared__ u16 sAh[128 * BK], sAl[128 * BK];
    __shared__ u16 sWih[64 * BK], sWil[64 * BK], sWch[64 * BK], sWcl[64 * BK];

    const int tid = threadIdx.x, wave = tid >> 6, lane = tid & 63;
    int bxi, byi;
    swizzle2048(blockIdx.x, bxi, byi);
    const size_t tileM = (size_t)byi * 128;
    const size_t h0 = (size_t)bxi * 64;
    const int waveM = (wave >> 1) * 64;
    const int waveH = (wave & 1) * 32;

    const int srow = lane >> 2, scol = (lane & 3) * 8;
    const size_t wr = (size_t)(wave * 16 + srow);
    const u16* gAh = Ahi + (tileM + wr) * K + scol;
    const u16* gAl = Alo + (tileM + wr) * K + scol;
    const u16* gWih = Whi + (h0 + wr) * K + scol;
    const u16* gWch = Whi + (4096 + h0 + wr) * K + scol;
    const u16* gWil = Wlo + (h0 + wr) * K + scol;
    const u16* gWcl = Wlo + (2048 + h0 + wr) * K + scol;
    u16* lAh0 = &sAh[(wave * 16) * BK];
    u16* lAh1 = &sAh[(wave * 16 + 64) * BK];
    u16* lAl0 = &sAl[(wave * 16) * BK];
    u16* lAl1 = &sAl[(wave * 16 + 64) * BK];
    u16* lWih = &sWih[(wave * 16) * BK];
    u16* lWil = &sWil[(wave * 16) * BK];
    u16* lWch = &sWch[(wave * 16) * BK];
    u16* lWcl = &sWcl[(wave * 16) * BK];

    f32x4 ai[4][2] = {}, ac[4][2] = {};
    const int arow = waveM + (lane & 15);
    const int wrow = waveH + (lane & 15);
    const int kq = (lane >> 4) * 8;

    for (int k0 = 0; k0 < K; k0 += BK) {
        gl_lds(gAh + k0, lAh0);
        gl_lds(gAh + (size_t)64 * K + k0, lAh1);
        gl_lds(gAl + k0, lAl0);
        gl_lds(gAl + (size_t)64 * K + k0, lAl1);
        gl_lds(gWih + k0, lWih);
        gl_lds(gWil + k0, lWil);
        gl_lds(gWch + k0, lWch);
        gl_lds(gWcl + k0, lWcl);
        __syncthreads();

        bf16x8 ah[4], al[4], wih[2], wil[2], wch[2], wcl[2];
#pragma unroll
        for (int i = 0; i < 4; ++i) {
            ah[i] = *(const bf16x8*)&sAh[(arow + i * 16) * BK + kq];
            al[i] = *(const bf16x8*)&sAl[(arow + i * 16) * BK + kq];
        }
#pragma unroll
        for (int j = 0; j < 2; ++j) {
            wih[j] = *(const bf16x8*)&sWih[(wrow + j * 16) * BK + kq];
            wil[j] = *(const bf16x8*)&sWil[(wrow + j * 16) * BK + kq];
            wch[j] = *(const bf16x8*)&sWch[(wrow + j * 16) * BK + kq];
            wcl[j] = *(const bf16x8*)&sWcl[(wrow + j * 16) * BK + kq];
        }
#pragma unroll
        for (int i = 0; i < 4; ++i)
#pragma unroll
            for (int j = 0; j < 2; ++j) {
                ai[i][j] = __builtin_amdgcn_mfma_f32_16x16x32_bf16(ah[i], wih[j], ai[i][j], 0, 0, 0);
                ai[i][j] = __builtin_amdgcn_mfma_f32_16x16x32_bf16(al[i], wih[j], ai[i][j], 0, 0, 0);
                ai[i][j] = __builtin_amdgcn_mfma_f32_16x16x32_bf16(ah[i], wil[j], ai[i][j], 0, 0, 0);
                ac[i][j] = __builtin_amdgcn_mfma_f32_16x16x32_bf16(ah[i], wch[j], ac[i][j], 0, 0, 0);
                ac[i][j] = __builtin_amdgcn_mfma_f32_16x16x32_bf16(al[i], wch[j], ac[i][j], 0, 0, 0);
                ac[i][j] = __builtin_amdgcn_mfma_f32_16x16x32_bf16(ah[i], wcl[j], ac[i][j], 0, 0, 0);
            }
        __syncthreads();
    }

    // epilogue + fused LSTM cell
    const int rq = (lane >> 4) * 4;
#pragma unroll
    for (int j = 0; j < 2; ++j) {
        const size_t h = h0 + waveH + j * 16 + (lane & 15);
        const float bi = bxv[h] + bhv[h];
        const float bc = bxv[4096 + h] + bhv[4096 + h];
#pragma unroll
        for (int i = 0; i < 4; ++i) {
            const size_t m0 = tileM + waveM + i * 16 + rq;
#pragma unroll
            for (int v = 0; v < 4; ++v) {
                const size_t m = m0 + v;
                const float iv = ai[i][j][v] + bi;
                const float cv = ac[i][j][v] + bc;
                const float f = b2f(Gfo[m * 4096 + h]);
                const float o = b2f(Gfo[m * 4096 + 2048 + h]);
                const float c_ = f * cx[m * 2048 + h] + iv * cv;
                ct[m * 2048 + h] = c_;
                U[m * 2048 + h] = f2b(o * fast_tanh(c_));
            }
        }
    }
}

// ============ proj: ht[B,512] = U[B,2048] * Wp[512,2048]^T, f32 out ============
__global__ __launch_bounds__(256) void gemm_proj(const u16* __restrict__ A,
                                                 const u16* __restrict__ W,
                                                 float* __restrict__ out) {
    constexpr int K = 2048, BK = 32;
    __shared__ u16 As[128 * BK];
    __shared__ u16 Ws[64 * BK];

    const int tid = threadIdx.x, wave = tid >> 6, lane = tid & 63;
    const size_t tileM = (size_t)blockIdx.y * 128;
    const size_t tileN = (size_t)blockIdx.x * 64;
    const int waveM = (wave >> 1) * 64;
    const int waveN = (wave & 1) * 32;

    const int srow = lane >> 2, scol = (lane & 3) * 8;
    const u16* Ag = A + (tileM + (size_t)(wave * 16 + srow)) * K + scol;
    const u16* Wg = W + (tileN + (size_t)(wave * 16 + srow)) * K + scol;
    u16* AsB0 = &As[(wave * 16) * BK];
    u16* AsB1 = &As[(wave * 16 + 64) * BK];
    u16* WsB0 = &Ws[(wave * 16) * BK];

    f32x4 acc[4][2] = {};
    const int arow = waveM + (lane & 15);
    const int wrow = waveN + (lane & 15);
    const int kq = (lane >> 4) * 8;

    for (int k0 = 0; k0 < K; k0 += BK) {
        gl_lds(Ag + k0, AsB0);
        gl_lds(Ag + (size_t)64 * K + k0, AsB1);
        gl_lds(Wg + k0, WsB0);
        __syncthreads();
        bf16x8 af[4], wf[2];
#pragma unroll
        for (int i = 0; i < 4; ++i) af[i] = *(const bf16x8*)&As[(arow + i * 16) * BK + kq];
#pragma unroll
        for (int j = 0; j < 2; ++j) wf[j] = *(const bf16x8*)&Ws[(wrow + j * 16) * BK + kq];
#pragma unroll
        for (int i = 0; i < 4; ++i)
#pragma unroll
            for (int j = 0; j < 2; ++j)
                acc[i][j] = __builtin_amdgcn_mfma_f32_16x16x32_bf16(af[i], wf[j], acc[i][j], 0, 0, 0);
        __syncthreads();
    }

    const int rq = (lane >> 4) * 4;
#pragma unroll
    for (int i = 0; i < 4; ++i) {
        const size_t rbase = tileM + waveM + i * 16 + rq;
#pragma unroll
        for (int j = 0; j < 2; ++j) {
            const size_t n = tileN + waveN + (lane & 15) + j * 16;
#pragma unroll
            for (int v = 0; v < 4; ++v)
                out[(rbase + v) * 512 + n] = acc[i][j][v];
        }
    }
}

// ============ launch ============
extern "C" void kernel_launch(void* const* d_in, const int* in_sizes, int n_in,
                              void* d_out, int out_size, void* d_ws, size_t ws_size,
                              hipStream_t stream) {
    const float* input  = (const float*)d_in[0];
    const float* hx     = (const float*)d_in[1];
    const float* cx     = (const float*)d_in[2];
    const float* w_x    = (const float*)d_in[3];
    const float* b_x    = (const float*)d_in[4];
    const float* w_h    = (const float*)d_in[5];
    const float* b_h    = (const float*)d_in[6];
    const float* w_proj = (const float*)d_in[7];

    constexpr int H = 2048, P = 512, B = 8192;

    char* ws = (char*)d_ws;
    u16* Ahi = (u16*)(ws);                 // [8192,1536] 25,165,824
    u16* Alo = (u16*)(ws + 25165824);      // [8192,1536] 25,165,824
    u16* Whi = (u16*)(ws + 50331648);      // [8192,1536] 25,165,824
    u16* Wlo = (u16*)(ws + 75497472);      // [4096,1536] 12,582,912
    u16* Gfo = (u16*)(ws + 88080384);      // [8192,4096] 67,108,864
    u16* U   = (u16*)(ws + 155189248);     // [8192,2048] 33,554,432
    u16* Wp  = (u16*)(ws + 188743680);     // [512,2048]   2,097,152

    float* ht = (float*)d_out;
    float* ct = (float*)d_out + (size_t)B * P;

    pack_A<<<B, 384, 0, stream>>>(input, hx, Ahi, Alo);
    pack_W<<<4 * H, 384, 0, stream>>>(w_x, w_h, Whi, Wlo);
    pack_flat_bf16<<<(P * H / 4) / 256, 256, 0, stream>>>(w_proj, Wp);

    gemm_fo<<<2048, 256, 0, stream>>>(Ahi, Whi, b_x, b_h, Gfo);
    gemm_ic_cell<<<2048, 256, 0, stream>>>(Ahi, Alo, Whi, Wlo, b_x, b_h,
                                           Gfo, cx, ct, U);
    gemm_proj<<<dim3(8, 64), 256, 0, stream>>>(U, Wp, ht);
}

// Round 4
// 709.824 us; speedup vs baseline: 1.3037x; 1.3018x over previous
//
#include <hip/hip_runtime.h>
#include <math.h>
#include <stdint.h>

#define DI static __device__ __forceinline__

typedef __bf16 bf16x8 __attribute__((ext_vector_type(8)));
typedef float f32x4 __attribute__((ext_vector_type(4)));
typedef float float4v __attribute__((ext_vector_type(4)));
typedef unsigned short u16;
typedef unsigned short u16x4 __attribute__((ext_vector_type(4)));

// ---- bf16 <-> f32 bit helpers (RNE) ----
DI float b2f(u16 s) {
    unsigned u = ((unsigned)s) << 16;
    float f;
    __builtin_memcpy(&f, &u, 4);
    return f;
}
DI u16 f2b(float f) {
    unsigned x;
    __builtin_memcpy(&x, &f, 4);
    unsigned r = x + 0x7FFFu + ((x >> 16) & 1u);
    return (u16)(r >> 16);
}

// ---- async global->LDS, 16B/lane; LDS dest = wave-uniform base + lane*16 ----
DI void gl_lds(const u16* g, u16* l) {
    __builtin_amdgcn_global_load_lds(
        (__attribute__((address_space(1))) void*)g,
        (__attribute__((address_space(3))) void*)l,
        16, 0, 0);
}

DI float fast_tanh(float x) {
    float xc = fminf(fmaxf(x, -15.f), 15.f);
    float e = __expf(2.0f * xc);
    return (e - 1.f) / (e + 1.f);
}

// ============ pack kernels ============
__global__ void pack_A(const float* __restrict__ inp, const float* __restrict__ hx,
                       u16* __restrict__ Ahi, u16* __restrict__ Alo) {
    const int r = blockIdx.x;
    const int k = threadIdx.x * 4;
    float4v v = (k < 1024) ? *(const float4v*)(inp + (size_t)r * 1024 + k)
                           : *(const float4v*)(hx + (size_t)r * 512 + (k - 1024));
    u16x4 h, l;
#pragma unroll
    for (int e = 0; e < 4; ++e) {
        h[e] = f2b(v[e]);
        l[e] = f2b(v[e] - b2f(h[e]));
    }
    *(u16x4*)(Ahi + (size_t)r * 1536 + k) = h;
    *(u16x4*)(Alo + (size_t)r * 1536 + k) = l;
}

// Whi all 8192 gate-rows; Wlo compacted: rows [0,2048)=i-lo, [2048,4096)=c-lo.
__global__ void pack_W(const float* __restrict__ wx, const float* __restrict__ wh,
                       u16* __restrict__ Whi, u16* __restrict__ Wlo) {
    const int g = blockIdx.x;
    const int k = threadIdx.x * 4;
    float4v v = (k < 1024) ? *(const float4v*)(wx + (size_t)g * 1024 + k)
                           : *(const float4v*)(wh + (size_t)g * 512 + (k - 1024));
    u16x4 h, l;
#pragma unroll
    for (int e = 0; e < 4; ++e) {
        h[e] = f2b(v[e]);
        l[e] = f2b(v[e] - b2f(h[e]));
    }
    *(u16x4*)(Whi + (size_t)g * 1536 + k) = h;
    int lr = -1;
    if (g < 2048) lr = g;
    else if (g >= 4096 && g < 6144) lr = g - 2048;
    if (lr >= 0) *(u16x4*)(Wlo + (size_t)lr * 1536 + k) = l;
}

__global__ void pack_flat_bf16(const float* __restrict__ src, u16* __restrict__ dst) {
    const size_t t = ((size_t)blockIdx.x * blockDim.x + threadIdx.x) * 4;
    float4v v = *(const float4v*)(src + t);
    u16x4 o;
#pragma unroll
    for (int e = 0; e < 4; ++e) o[e] = f2b(v[e]);
    *(u16x4*)(dst + t) = o;
}

// ---- XCD swizzle: linear id -> (bx in [0,32), by in [0,64)) ----
DI void swizzle2048(int id, int& bx, int& by) {
    const int xcd = id & 7;
    const int j = id >> 3;
    bx = xcd * 4 + (j & 3);
    by = j >> 2;
}

// ============ G1: f,o gates, plain bf16, double-buffered LDS ============
__global__ __launch_bounds__(256, 2) void gemm_fo(const u16* __restrict__ A,
                                                  const u16* __restrict__ W,
                                                  const float* __restrict__ bxv,
                                                  const float* __restrict__ bhv,
                                                  u16* __restrict__ out) {
    constexpr int K = 1536, BK = 32;
    constexpr int AB = 128 * BK;  // per-buffer elements
    __shared__ u16 As[2 * AB];
    __shared__ u16 Ws[2 * AB];

    const int tid = threadIdx.x, wave = tid >> 6, lane = tid & 63;
    int bxi, byi;
    swizzle2048(blockIdx.x, bxi, byi);
    const size_t tileM = (size_t)byi * 128;
    const size_t wrow0 = (bxi < 16) ? (2048 + (size_t)bxi * 128)
                                    : (6144 + (size_t)(bxi - 16) * 128);
    const size_t ncol0 = (size_t)bxi * 128;
    const int waveM = (wave >> 1) * 64;
    const int waveN = (wave & 1) * 64;

    const int srow = lane >> 2, scol = (lane & 3) * 8;
    const u16* Ag = A + (tileM + (size_t)(wave * 16 + srow)) * K + scol;
    const u16* Wg = W + (wrow0 + (size_t)(wave * 16 + srow)) * K + scol;
    const int lA0 = (wave * 16) * BK;
    const int lA1 = (wave * 16 + 64) * BK;

    f32x4 acc[4][4] = {};
    const int arow = waveM + (lane & 15);
    const int wrow = waveN + (lane & 15);
    const int kq = (lane >> 4) * 8;

#define STAGE_FO(b, k0)                              \
    do {                                             \
        gl_lds(Ag + (k0), &As[(b)*AB + lA0]);        \
        gl_lds(Ag + (size_t)64 * K + (k0), &As[(b)*AB + lA1]); \
        gl_lds(Wg + (k0), &Ws[(b)*AB + lA0]);        \
        gl_lds(Wg + (size_t)64 * K + (k0), &Ws[(b)*AB + lA1]); \
    } while (0)

#define COMPUTE_FO(b)                                                          \
    do {                                                                       \
        bf16x8 af[4], wf[4];                                                   \
        _Pragma("unroll") for (int i = 0; i < 4; ++i)                          \
            af[i] = *(const bf16x8*)&As[(b)*AB + (arow + i * 16) * BK + kq];   \
        _Pragma("unroll") for (int j = 0; j < 4; ++j)                          \
            wf[j] = *(const bf16x8*)&Ws[(b)*AB + (wrow + j * 16) * BK + kq];   \
        _Pragma("unroll") for (int i = 0; i < 4; ++i)                          \
            _Pragma("unroll") for (int j = 0; j < 4; ++j)                      \
                acc[i][j] = __builtin_amdgcn_mfma_f32_16x16x32_bf16(           \
                    af[i], wf[j], acc[i][j], 0, 0, 0);                         \
    } while (0)

    STAGE_FO(0, 0);
    __syncthreads();
    for (int k0 = 0; k0 < K; k0 += 2 * BK) {
        STAGE_FO(1, k0 + BK);
        COMPUTE_FO(0);
        __syncthreads();
        if (k0 + 2 * BK < K) STAGE_FO(0, k0 + 2 * BK);
        COMPUTE_FO(1);
        __syncthreads();
    }
#undef STAGE_FO
#undef COMPUTE_FO

    const int rq = (lane >> 4) * 4;
#pragma unroll
    for (int i = 0; i < 4; ++i) {
        const size_t rbase = tileM + waveM + i * 16 + rq;
#pragma unroll
        for (int j = 0; j < 4; ++j) {
            const int nl = waveN + (lane & 15) + j * 16;
            const float bias = bxv[wrow0 + nl] + bhv[wrow0 + nl];
#pragma unroll
            for (int v = 0; v < 4; ++v)
                out[(rbase + v) * 4096 + ncol0 + nl] = f2b(acc[i][j][v] + bias);
        }
    }
}

// ============ G2: i,c split-bf16 + fused cell, double-buffered LDS ============
__global__ __launch_bounds__(256, 2) void gemm_ic_cell(
    const u16* __restrict__ Ahi, const u16* __restrict__ Alo,
    const u16* __restrict__ Whi, const u16* __restrict__ Wlo,
    const float* __restrict__ bxv, const float* __restrict__ bhv,
    const u16* __restrict__ Gfo, const float* __restrict__ cx,
    float* __restrict__ ct, u16* __restrict__ U) {
    constexpr int K = 1536, BK = 32;
    constexpr int AB = 128 * BK;  // A per-buffer elements
    constexpr int WB = 64 * BK;   // W per-buffer elements
    __shared__ u16 sAh[2 * AB], sAl[2 * AB];
    __shared__ u16 sWih[2 * WB], sWil[2 * WB], sWch[2 * WB], sWcl[2 * WB];

    const int tid = threadIdx.x, wave = tid >> 6, lane = tid & 63;
    int bxi, byi;
    swizzle2048(blockIdx.x, bxi, byi);
    const size_t tileM = (size_t)byi * 128;
    const size_t h0 = (size_t)bxi * 64;
    const int waveM = (wave >> 1) * 64;
    const int waveH = (wave & 1) * 32;

    const int srow = lane >> 2, scol = (lane & 3) * 8;
    const size_t wr = (size_t)(wave * 16 + srow);
    const u16* gAh = Ahi + (tileM + wr) * K + scol;
    const u16* gAl = Alo + (tileM + wr) * K + scol;
    const u16* gWih = Whi + (h0 + wr) * K + scol;
    const u16* gWch = Whi + (4096 + h0 + wr) * K + scol;
    const u16* gWil = Wlo + (h0 + wr) * K + scol;
    const u16* gWcl = Wlo + (2048 + h0 + wr) * K + scol;
    const int lA0 = (wave * 16) * BK;
    const int lA1 = (wave * 16 + 64) * BK;
    const int lW0 = (wave * 16) * BK;

    f32x4 ai[4][2] = {}, ac[4][2] = {};
    const int arow = waveM + (lane & 15);
    const int wrow = waveH + (lane & 15);
    const int kq = (lane >> 4) * 8;

#define STAGE_IC(b, k0)                                          \
    do {                                                         \
        gl_lds(gAh + (k0), &sAh[(b)*AB + lA0]);                  \
        gl_lds(gAh + (size_t)64 * K + (k0), &sAh[(b)*AB + lA1]); \
        gl_lds(gAl + (k0), &sAl[(b)*AB + lA0]);                  \
        gl_lds(gAl + (size_t)64 * K + (k0), &sAl[(b)*AB + lA1]); \
        gl_lds(gWih + (k0), &sWih[(b)*WB + lW0]);                \
        gl_lds(gWil + (k0), &sWil[(b)*WB + lW0]);                \
        gl_lds(gWch + (k0), &sWch[(b)*WB + lW0]);                \
        gl_lds(gWcl + (k0), &sWcl[(b)*WB + lW0]);                \
    } while (0)

#define COMPUTE_IC(b)                                                            \
    do {                                                                         \
        bf16x8 ah[4], al[4], wih[2], wil[2], wch[2], wcl[2];                     \
        _Pragma("unroll") for (int i = 0; i < 4; ++i) {                          \
            ah[i] = *(const bf16x8*)&sAh[(b)*AB + (arow + i * 16) * BK + kq];    \
            al[i] = *(const bf16x8*)&sAl[(b)*AB + (arow + i * 16) * BK + kq];    \
        }                                                                        \
        _Pragma("unroll") for (int j = 0; j < 2; ++j) {                          \
            wih[j] = *(const bf16x8*)&sWih[(b)*WB + (wrow + j * 16) * BK + kq];  \
            wil[j] = *(const bf16x8*)&sWil[(b)*WB + (wrow + j * 16) * BK + kq];  \
            wch[j] = *(const bf16x8*)&sWch[(b)*WB + (wrow + j * 16) * BK + kq];  \
            wcl[j] = *(const bf16x8*)&sWcl[(b)*WB + (wrow + j * 16) * BK + kq];  \
        }                                                                        \
        _Pragma("unroll") for (int i = 0; i < 4; ++i)                            \
            _Pragma("unroll") for (int j = 0; j < 2; ++j) {                      \
                ai[i][j] = __builtin_amdgcn_mfma_f32_16x16x32_bf16(ah[i], wih[j], ai[i][j], 0, 0, 0); \
                ai[i][j] = __builtin_amdgcn_mfma_f32_16x16x32_bf16(al[i], wih[j], ai[i][j], 0, 0, 0); \
                ai[i][j] = __builtin_amdgcn_mfma_f32_16x16x32_bf16(ah[i], wil[j], ai[i][j], 0, 0, 0); \
                ac[i][j] = __builtin_amdgcn_mfma_f32_16x16x32_bf16(ah[i], wch[j], ac[i][j], 0, 0, 0); \
                ac[i][j] = __builtin_amdgcn_mfma_f32_16x16x32_bf16(al[i], wch[j], ac[i][j], 0, 0, 0); \
                ac[i][j] = __builtin_amdgcn_mfma_f32_16x16x32_bf16(ah[i], wcl[j], ac[i][j], 0, 0, 0); \
            }                                                                    \
    } while (0)

    STAGE_IC(0, 0);
    __syncthreads();
    for (int k0 = 0; k0 < K; k0 += 2 * BK) {
        STAGE_IC(1, k0 + BK);
        COMPUTE_IC(0);
        __syncthreads();
        if (k0 + 2 * BK < K) STAGE_IC(0, k0 + 2 * BK);
        COMPUTE_IC(1);
        __syncthreads();
    }
#undef STAGE_IC
#undef COMPUTE_IC

    // epilogue + fused LSTM cell
    const int rq = (lane >> 4) * 4;
#pragma unroll
    for (int j = 0; j < 2; ++j) {
        const size_t h = h0 + waveH + j * 16 + (lane & 15);
        const float bi = bxv[h] + bhv[h];
        const float bc = bxv[4096 + h] + bhv[4096 + h];
#pragma unroll
        for (int i = 0; i < 4; ++i) {
            const size_t m0 = tileM + waveM + i * 16 + rq;
#pragma unroll
            for (int v = 0; v < 4; ++v) {
                const size_t m = m0 + v;
                const float iv = ai[i][j][v] + bi;
                const float cv = ac[i][j][v] + bc;
                const float f = b2f(Gfo[m * 4096 + h]);
                const float o = b2f(Gfo[m * 4096 + 2048 + h]);
                const float c_ = f * cx[m * 2048 + h] + iv * cv;
                ct[m * 2048 + h] = c_;
                U[m * 2048 + h] = f2b(o * fast_tanh(c_));
            }
        }
    }
}

// ============ proj: ht[B,512] = U[B,2048] * Wp[512,2048]^T, dbuf ============
__global__ __launch_bounds__(256, 2) void gemm_proj(const u16* __restrict__ A,
                                                    const u16* __restrict__ W,
                                                    float* __restrict__ out) {
    constexpr int K = 2048, BK = 32;
    constexpr int AB = 128 * BK;
    constexpr int WB = 64 * BK;
    __shared__ u16 As[2 * AB];
    __shared__ u16 Ws[2 * WB];

    const int tid = threadIdx.x, wave = tid >> 6, lane = tid & 63;
    const size_t tileM = (size_t)blockIdx.y * 128;
    const size_t tileN = (size_t)blockIdx.x * 64;
    const int waveM = (wave >> 1) * 64;
    const int waveN = (wave & 1) * 32;

    const int srow = lane >> 2, scol = (lane & 3) * 8;
    const u16* Ag = A + (tileM + (size_t)(wave * 16 + srow)) * K + scol;
    const u16* Wg = W + (tileN + (size_t)(wave * 16 + srow)) * K + scol;
    const int lA0 = (wave * 16) * BK;
    const int lA1 = (wave * 16 + 64) * BK;

    f32x4 acc[4][2] = {};
    const int arow = waveM + (lane & 15);
    const int wrow = waveN + (lane & 15);
    const int kq = (lane >> 4) * 8;

#define STAGE_PR(b, k0)                                        \
    do {                                                       \
        gl_lds(Ag + (k0), &As[(b)*AB + lA0]);                  \
        gl_lds(Ag + (size_t)64 * K + (k0), &As[(b)*AB + lA1]); \
        gl_lds(Wg + (k0), &Ws[(b)*WB + lA0]);                  \
    } while (0)

#define COMPUTE_PR(b)                                                          \
    do {                                                                       \
        bf16x8 af[4], wf[2];                                                   \
        _Pragma("unroll") for (int i = 0; i < 4; ++i)                          \
            af[i] = *(const bf16x8*)&As[(b)*AB + (arow + i * 16) * BK + kq];   \
        _Pragma("unroll") for (int j = 0; j < 2; ++j)                          \
            wf[j] = *(const bf16x8*)&Ws[(b)*WB + (wrow + j * 16) * BK + kq];   \
        _Pragma("unroll") for (int i = 0; i < 4; ++i)                          \
            _Pragma("unroll") for (int j = 0; j < 2; ++j)                      \
                acc[i][j] = __builtin_amdgcn_mfma_f32_16x16x32_bf16(           \
                    af[i], wf[j], acc[i][j], 0, 0, 0);                         \
    } while (0)

    STAGE_PR(0, 0);
    __syncthreads();
    for (int k0 = 0; k0 < K; k0 += 2 * BK) {
        STAGE_PR(1, k0 + BK);
        COMPUTE_PR(0);
        __syncthreads();
        if (k0 + 2 * BK < K) STAGE_PR(0, k0 + 2 * BK);
        COMPUTE_PR(1);
        __syncthreads();
    }
#undef STAGE_PR
#undef COMPUTE_PR

    const int rq = (lane >> 4) * 4;
#pragma unroll
    for (int i = 0; i < 4; ++i) {
        const size_t rbase = tileM + waveM + i * 16 + rq;
#pragma unroll
        for (int j = 0; j < 2; ++j) {
            const size_t n = tileN + waveN + (lane & 15) + j * 16;
#pragma unroll
            for (int v = 0; v < 4; ++v)
                out[(rbase + v) * 512 + n] = acc[i][j][v];
        }
    }
}

// ============ launch ============
extern "C" void kernel_launch(void* const* d_in, const int* in_sizes, int n_in,
                              void* d_out, int out_size, void* d_ws, size_t ws_size,
                              hipStream_t stream) {
    const float* input  = (const float*)d_in[0];
    const float* hx     = (const float*)d_in[1];
    const float* cx     = (const float*)d_in[2];
    const float* w_x    = (const float*)d_in[3];
    const float* b_x    = (const float*)d_in[4];
    const float* w_h    = (const float*)d_in[5];
    const float* b_h    = (const float*)d_in[6];
    const float* w_proj = (const float*)d_in[7];

    constexpr int H = 2048, P = 512, B = 8192;

    char* ws = (char*)d_ws;
    u16* Ahi = (u16*)(ws);                 // [8192,1536] 25,165,824
    u16* Alo = (u16*)(ws + 25165824);      // [8192,1536] 25,165,824
    u16* Whi = (u16*)(ws + 50331648);      // [8192,1536] 25,165,824
    u16* Wlo = (u16*)(ws + 75497472);      // [4096,1536] 12,582,912
    u16* Gfo = (u16*)(ws + 88080384);      // [8192,4096] 67,108,864
    u16* U   = (u16*)(ws + 155189248);     // [8192,2048] 33,554,432
    u16* Wp  = (u16*)(ws + 188743680);     // [512,2048]   2,097,152

    float* ht = (float*)d_out;
    float* ct = (float*)d_out + (size_t)B * P;

    pack_A<<<B, 384, 0, stream>>>(input, hx, Ahi, Alo);
    pack_W<<<4 * H, 384, 0, stream>>>(w_x, w_h, Whi, Wlo);
    pack_flat_bf16<<<(P * H / 4) / 256, 256, 0, stream>>>(w_proj, Wp);

    gemm_fo<<<2048, 256, 0, stream>>>(Ahi, Whi, b_x, b_h, Gfo);
    gemm_ic_cell<<<2048, 256, 0, stream>>>(Ahi, Alo, Whi, Wlo, b_x, b_h,
                                           Gfo, cx, ct, U);
    gemm_proj<<<dim3(8, 64), 256, 0, stream>>>(U, Wp, ht);
}